// Round 1
// baseline (1397.364 us; speedup 1.0000x reference)
//
#include <hip/hip_runtime.h>
#include <math.h>

// LocalityAttention: Q=q@Wq^T+bq; K=k@Wk^T+bk; V=v@Wv^T+bv;
// S = (Q K^T)/temp with diagonal masked to -1e4; P = softmax(S); out = P V.
// All fp32 (scores need fp32 accuracy: logit std ~27, near-one-hot softmax).

#define BM 128
#define BN 128
#define BKT 8

template<bool TRANSB, bool BIAS>
__global__ __launch_bounds__(256)
void gemm_tile(const float* __restrict__ A, const float* __restrict__ Bm,
               const float* __restrict__ bias, float* __restrict__ C,
               int M, int N, int K,
               long long sA, long long sB, long long sC)
{
    // C[m,n] = sum_k A[m,k] * (TRANSB ? Bm[n,k] : Bm[k,n])  (+ bias[n])
    // All of M%128==0, N%128==0, K%8==0 hold for every call here -> no guards.
    __shared__ float As[BKT][BM];
    __shared__ float Bs[BKT][BN];

    const int tid = threadIdx.x;
    const int bz  = blockIdx.z;
    const float* Ab = A  + (long long)bz * sA;
    const float* Bb = Bm + (long long)bz * sB;
    float*       Cb = C  + (long long)bz * sC;

    const int m0 = blockIdx.y * BM;
    const int n0 = blockIdx.x * BN;

    // A tile: 128 rows x 8 k -> 256 float4 (one per thread)
    const int arow = tid >> 1;
    const int acol = (tid & 1) * 4;
    // B tile (TRANSB): 128 n-rows x 8 k
    const int brow_t = tid >> 1;
    const int bcol_t = (tid & 1) * 4;
    // B tile (NN): 8 k-rows x 128 n
    const int brow_n = tid >> 5;
    const int bcol_n = (tid & 31) * 4;

    const int tx = tid & 15;   // column group
    const int ty = tid >> 4;   // row group

    float acc[8][8];
    #pragma unroll
    for (int i = 0; i < 8; ++i)
        #pragma unroll
        for (int j = 0; j < 8; ++j) acc[i][j] = 0.f;

    for (int k0 = 0; k0 < K; k0 += BKT) {
        float4 av = *(const float4*)&Ab[(long long)(m0 + arow) * K + k0 + acol];
        As[acol + 0][arow] = av.x;
        As[acol + 1][arow] = av.y;
        As[acol + 2][arow] = av.z;
        As[acol + 3][arow] = av.w;
        if (TRANSB) {
            float4 bv = *(const float4*)&Bb[(long long)(n0 + brow_t) * K + k0 + bcol_t];
            Bs[bcol_t + 0][brow_t] = bv.x;
            Bs[bcol_t + 1][brow_t] = bv.y;
            Bs[bcol_t + 2][brow_t] = bv.z;
            Bs[bcol_t + 3][brow_t] = bv.w;
        } else {
            float4 bv = *(const float4*)&Bb[(long long)(k0 + brow_n) * N + n0 + bcol_n];
            *(float4*)&Bs[brow_n][bcol_n] = bv;
        }
        __syncthreads();

        #pragma unroll
        for (int kk = 0; kk < BKT; ++kk) {
            float4 a0 = *(const float4*)&As[kk][ty * 4];
            float4 a1 = *(const float4*)&As[kk][ty * 4 + 64];
            float4 b0 = *(const float4*)&Bs[kk][tx * 4];
            float4 b1 = *(const float4*)&Bs[kk][tx * 4 + 64];
            float a[8] = {a0.x, a0.y, a0.z, a0.w, a1.x, a1.y, a1.z, a1.w};
            float b[8] = {b0.x, b0.y, b0.z, b0.w, b1.x, b1.y, b1.z, b1.w};
            #pragma unroll
            for (int i = 0; i < 8; ++i)
                #pragma unroll
                for (int j = 0; j < 8; ++j)
                    acc[i][j] = fmaf(a[i], b[j], acc[i][j]);
        }
        __syncthreads();
    }

    #pragma unroll
    for (int ih = 0; ih < 2; ++ih) {
        #pragma unroll
        for (int i = 0; i < 4; ++i) {
            const int m = m0 + ty * 4 + ih * 64 + i;
            #pragma unroll
            for (int jh = 0; jh < 2; ++jh) {
                const int n = n0 + tx * 4 + jh * 64;
                float4 r;
                r.x = acc[ih * 4 + i][jh * 4 + 0];
                r.y = acc[ih * 4 + i][jh * 4 + 1];
                r.z = acc[ih * 4 + i][jh * 4 + 2];
                r.w = acc[ih * 4 + i][jh * 4 + 3];
                if (BIAS) {
                    float4 bb = *(const float4*)&bias[n];
                    r.x += bb.x; r.y += bb.y; r.z += bb.z; r.w += bb.w;
                }
                *(float4*)&Cb[(long long)m * N + n] = r;
            }
        }
    }
}

// Row softmax with diagonal self-exclusion. One block per row (S=1024, 256 thr x 4).
__global__ __launch_bounds__(256)
void softmax_diag_kernel(float* __restrict__ P, const float* __restrict__ tptr, int S)
{
    const int row = blockIdx.x;          // b*S + i
    const int i   = row % S;
    float* rp = P + (long long)row * S;
    const int tid = threadIdx.x;
    const float invt = 1.0f / tptr[0];

    float4 v = *(const float4*)&rp[tid * 4];
    float vals[4] = {v.x, v.y, v.z, v.w};
    #pragma unroll
    for (int j = 0; j < 4; ++j) {
        vals[j] *= invt;
        if (tid * 4 + j == i) vals[j] = -INFINITY;  // == ref's -1e4: exp underflows to 0
    }

    float mx = fmaxf(fmaxf(vals[0], vals[1]), fmaxf(vals[2], vals[3]));
    #pragma unroll
    for (int off = 32; off > 0; off >>= 1)
        mx = fmaxf(mx, __shfl_down(mx, off, 64));

    __shared__ float smax[4], ssum[4];
    const int wv = tid >> 6, ln = tid & 63;
    if (ln == 0) smax[wv] = mx;
    __syncthreads();
    mx = fmaxf(fmaxf(smax[0], smax[1]), fmaxf(smax[2], smax[3]));

    float e[4];
    float s = 0.f;
    #pragma unroll
    for (int j = 0; j < 4; ++j) { e[j] = expf(vals[j] - mx); s += e[j]; }
    #pragma unroll
    for (int off = 32; off > 0; off >>= 1)
        s += __shfl_down(s, off, 64);
    if (ln == 0) ssum[wv] = s;
    __syncthreads();
    s = ssum[0] + ssum[1] + ssum[2] + ssum[3];

    const float inv = 1.0f / s;
    float4 o;
    o.x = e[0] * inv; o.y = e[1] * inv; o.z = e[2] * inv; o.w = e[3] * inv;
    *(float4*)&rp[tid * 4] = o;
}

extern "C" void kernel_launch(void* const* d_in, const int* in_sizes, int n_in,
                              void* d_out, int out_size, void* d_ws, size_t ws_size,
                              hipStream_t stream)
{
    const float* q    = (const float*)d_in[0];
    const float* k    = (const float*)d_in[1];
    const float* v    = (const float*)d_in[2];
    const float* Wq   = (const float*)d_in[3];
    const float* bq   = (const float*)d_in[4];
    const float* Wk   = (const float*)d_in[5];
    const float* bk   = (const float*)d_in[6];
    const float* Wv   = (const float*)d_in[7];
    const float* bv   = (const float*)d_in[8];
    const float* temp = (const float*)d_in[9];

    const int B = 16, S = 1024, D = 768;
    const long long nQ = (long long)B * S * D;   // 12,582,912 floats each
    float* Q  = (float*)d_ws;
    float* Kp = Q  + nQ;
    float* Vp = Kp + nQ;
    float* P  = Vp + nQ;                         // [B,S,S] = 16,777,216 floats
    // ws requirement: (3*12.58M + 16.78M)*4B = ~208 MiB

    dim3 blk(256);

    // Projections: [B*S, D] x [D, D]^T  (M=16384, N=768, K=768)
    dim3 g1(D / BN, (B * S) / BM, 1);
    gemm_tile<true, true><<<g1, blk, 0, stream>>>(q, Wq, bq, Q,  B * S, D, D, 0, 0, 0);
    gemm_tile<true, true><<<g1, blk, 0, stream>>>(k, Wk, bk, Kp, B * S, D, D, 0, 0, 0);
    gemm_tile<true, true><<<g1, blk, 0, stream>>>(v, Wv, bv, Vp, B * S, D, D, 0, 0, 0);

    // Scores: per batch  Q[b] x K[b]^T  (M=N=1024, K=768)
    dim3 g2(S / BN, S / BM, B);
    gemm_tile<true, false><<<g2, blk, 0, stream>>>(Q, Kp, nullptr, P, S, S, D,
                                                   (long long)S * D, (long long)S * D,
                                                   (long long)S * S);

    // Masked softmax over rows (temperature applied here)
    softmax_diag_kernel<<<B * S, blk, 0, stream>>>(P, temp, S);

    // Out: per batch  P[b] x V[b]  (M=1024, N=768, K=1024), NN
    dim3 g3(D / BN, S / BM, B);
    gemm_tile<false, false><<<g3, blk, 0, stream>>>(P, Vp, nullptr, (float*)d_out, S, D, S,
                                                    (long long)S * S, (long long)S * D,
                                                    (long long)S * D);
}

// Round 2
// 433.035 us; speedup vs baseline: 3.2269x; 3.2269x over previous
//
#include <hip/hip_runtime.h>
#include <hip/hip_bf16.h>
#include <math.h>

// LocalityAttention via split-bf16 MFMA.
// q,k,Wq,Wk,Q,K,scores use 2-term bf16 split (hi+lo, 3 MFMA passes) -> ~16-bit
// mantissa accuracy on the logits (noise ~8e-4, vs bf16-only ~0.15 which fails).
// v,Wv,V,P use plain bf16 (output-side error ~1e-2, under threshold).

typedef __attribute__((ext_vector_type(8))) short short8;
typedef __attribute__((ext_vector_type(4))) float f32x4;

__device__ __forceinline__ ushort f2bf(float x) {
    __hip_bfloat16 h = __float2bfloat16(x);
    return *(ushort*)&h;
}
__device__ __forceinline__ float bf2f(ushort u) {
    __hip_bfloat16 h;
    *(ushort*)&h = u;
    return __bfloat162float(h);
}

template<typename T>
__device__ __forceinline__ void async_copy16(T* lds, const T* g) {
    __builtin_amdgcn_global_load_lds(
        (const __attribute__((address_space(1))) unsigned int*)g,
        (__attribute__((address_space(3))) unsigned int*)lds, 16, 0, 0);
}

#define BM 128
#define BN 128
#define BK 32

// C[m,n] = sum_k A[m,k]*B[n,k]   (TRANSB everywhere: B staged row-major [n][k])
// SPLIT: A,B given as (hi,lo) bf16 pairs; accumulate hi*hi + hi*lo + lo*hi.
// EPI: 0 = fp32 store to C0; 1 = bf16 split store to C0(hi),C1(lo); 2 = bf16 to C0.
// BIAS: 0 none; 1 bias[col]; 2 bias[row].
template<int SPLIT, int EPI, int BIAS>
__global__ __launch_bounds__(256, 2)
void mfma_gemm(const ushort* __restrict__ Ah, const ushort* __restrict__ Al,
               const ushort* __restrict__ Bh, const ushort* __restrict__ Bl,
               const float* __restrict__ bias,
               void* __restrict__ C0, void* __restrict__ C1,
               int K, int lda, int ldb, int ldc,
               long long sA, long long sB, long long sC)
{
    __shared__ ushort sAh[BM * BK];
    __shared__ ushort sBh[BN * BK];
    __shared__ ushort sAl[SPLIT ? BM * BK : 4];
    __shared__ ushort sBl[SPLIT ? BN * BK : 4];

    const int tid = threadIdx.x;
    const long long bz = blockIdx.z;
    const int m0 = blockIdx.y * BM;
    const int n0 = blockIdx.x * BN;

    const ushort* A0 = Ah + bz * sA;
    const ushort* B0 = Bh + bz * sB;
    const ushort* A1 = SPLIT ? Al + bz * sA : nullptr;
    const ushort* B1 = SPLIT ? Bl + bz * sB : nullptr;

    // loader: flat byte f = tid*16 + it*4096 -> row = f/64, slot = (f/16)&3
    // LDS is the swizzled layout: physical slot p holds global slot p^(row&3).
    const int lrow  = tid >> 2;
    const int lslot = tid & 3;

    const int lane = tid & 63;
    const int wv   = tid >> 6;
    const int wm   = wv >> 1, wn = wv & 1;
    const int fr   = lane & 15;       // fragment row (A) / col-row (B)
    const int fs   = lane >> 4;       // k-slot (8 bf16 = 16B each)
    const int sw   = fs ^ (fr & 3);   // swizzled read slot
    const int abase = (wm * 64 + fr) * BK + sw * 8;
    const int bbase = (wn * 64 + fr) * BK + sw * 8;

    f32x4 acc[4][4] = {};

    for (int kt = 0; kt < K; kt += BK) {
        #pragma unroll
        for (int it = 0; it < 2; ++it) {
            const int row = lrow + it * 64;
            const int gsl = (lslot ^ (row & 3)) << 3;       // element offset in row
            const size_t loff = (size_t)tid * 8 + (size_t)it * 2048;
            async_copy16(&sAh[loff], A0 + (size_t)(m0 + row) * lda + kt + gsl);
            async_copy16(&sBh[loff], B0 + (size_t)(n0 + row) * ldb + kt + gsl);
            if (SPLIT) {
                async_copy16(&sAl[loff], A1 + (size_t)(m0 + row) * lda + kt + gsl);
                async_copy16(&sBl[loff], B1 + (size_t)(n0 + row) * ldb + kt + gsl);
            }
        }
        __syncthreads();

        short8 ah[4], bh[4], al[4], bl[4];
        #pragma unroll
        for (int i = 0; i < 4; ++i) {
            ah[i] = *(const short8*)&sAh[abase + i * 512];
            bh[i] = *(const short8*)&sBh[bbase + i * 512];
            if (SPLIT) {
                al[i] = *(const short8*)&sAl[abase + i * 512];
                bl[i] = *(const short8*)&sBl[bbase + i * 512];
            }
        }
        #pragma unroll
        for (int mi = 0; mi < 4; ++mi)
            #pragma unroll
            for (int ni = 0; ni < 4; ++ni) {
                acc[mi][ni] = __builtin_amdgcn_mfma_f32_16x16x32_bf16(
                    ah[mi], bh[ni], acc[mi][ni], 0, 0, 0);
                if (SPLIT) {
                    acc[mi][ni] = __builtin_amdgcn_mfma_f32_16x16x32_bf16(
                        ah[mi], bl[ni], acc[mi][ni], 0, 0, 0);
                    acc[mi][ni] = __builtin_amdgcn_mfma_f32_16x16x32_bf16(
                        al[mi], bh[ni], acc[mi][ni], 0, 0, 0);
                }
            }
        __syncthreads();
    }

    // epilogue: D row = (lane>>4)*4 + r, col = lane&15 (verified m89 mapping)
    const int er = fs * 4;
    #pragma unroll
    for (int mi = 0; mi < 4; ++mi) {
        #pragma unroll
        for (int ni = 0; ni < 4; ++ni) {
            const int col = n0 + wn * 64 + ni * 16 + fr;
            #pragma unroll
            for (int r = 0; r < 4; ++r) {
                const int row = m0 + wm * 64 + mi * 16 + er + r;
                float vv = acc[mi][ni][r];
                if (BIAS == 1) vv += bias[col];
                if (BIAS == 2) vv += bias[row];
                const size_t idx = (size_t)bz * sC + (size_t)row * ldc + col;
                if (EPI == 0) {
                    ((float*)C0)[idx] = vv;
                } else if (EPI == 1) {
                    const ushort h = f2bf(vv);
                    ((ushort*)C0)[idx] = h;
                    ((ushort*)C1)[idx] = f2bf(vv - bf2f(h));
                } else {
                    ((ushort*)C0)[idx] = f2bf(vv);
                }
            }
        }
    }
}

// fp32 -> bf16 hi (+lo) split, vectorized
template<bool LO>
__global__ __launch_bounds__(256)
void split_kernel(const float* __restrict__ src, ushort* __restrict__ hi,
                  ushort* __restrict__ lo, long long n)
{
    long long i = ((long long)blockIdx.x * 256 + threadIdx.x) * 4;
    const long long stride = (long long)gridDim.x * 1024;
    for (; i < n; i += stride) {
        float4 v = *(const float4*)&src[i];
        float xs[4] = {v.x, v.y, v.z, v.w};
        ushort4 h, l;
        ushort hh[4], ll[4];
        #pragma unroll
        for (int j = 0; j < 4; ++j) {
            hh[j] = f2bf(xs[j]);
            if (LO) ll[j] = f2bf(xs[j] - bf2f(hh[j]));
        }
        h.x = hh[0]; h.y = hh[1]; h.z = hh[2]; h.w = hh[3];
        *(ushort4*)&hi[i] = h;
        if (LO) {
            l.x = ll[0]; l.y = ll[1]; l.z = ll[2]; l.w = ll[3];
            *(ushort4*)&lo[i] = l;
        }
    }
}

// Row softmax with diag mask; reads fp32 row, writes bf16 P IN-PLACE over the
// first half of the row (all reads complete before the first barrier).
__global__ __launch_bounds__(256)
void softmax_diag(float* __restrict__ P, const float* __restrict__ tptr, int S)
{
    const int row = blockIdx.x;
    const int i   = row % S;
    float* rp = P + (long long)row * S;
    const int tid = threadIdx.x;
    const float invt = 1.0f / tptr[0];

    float4 v = *(const float4*)&rp[tid * 4];
    float vals[4] = {v.x, v.y, v.z, v.w};
    #pragma unroll
    for (int j = 0; j < 4; ++j) {
        vals[j] *= invt;
        if (tid * 4 + j == i) vals[j] = -INFINITY;
    }

    float mx = fmaxf(fmaxf(vals[0], vals[1]), fmaxf(vals[2], vals[3]));
    #pragma unroll
    for (int off = 32; off > 0; off >>= 1)
        mx = fmaxf(mx, __shfl_down(mx, off, 64));

    __shared__ float smax[4], ssum[4];
    const int wv = tid >> 6, ln = tid & 63;
    if (ln == 0) smax[wv] = mx;
    __syncthreads();
    mx = fmaxf(fmaxf(smax[0], smax[1]), fmaxf(smax[2], smax[3]));

    float e[4];
    float s = 0.f;
    #pragma unroll
    for (int j = 0; j < 4; ++j) { e[j] = expf(vals[j] - mx); s += e[j]; }
    #pragma unroll
    for (int off = 32; off > 0; off >>= 1)
        s += __shfl_down(s, off, 64);
    if (ln == 0) ssum[wv] = s;
    __syncthreads();
    s = ssum[0] + ssum[1] + ssum[2] + ssum[3];

    const float inv = 1.0f / s;
    ushort4 o;
    o.x = f2bf(e[0] * inv);
    o.y = f2bf(e[1] * inv);
    o.z = f2bf(e[2] * inv);
    o.w = f2bf(e[3] * inv);
    *(ushort4*)&((ushort*)rp)[tid * 4] = o;
}

extern "C" void kernel_launch(void* const* d_in, const int* in_sizes, int n_in,
                              void* d_out, int out_size, void* d_ws, size_t ws_size,
                              hipStream_t stream)
{
    const float* q    = (const float*)d_in[0];
    const float* k    = (const float*)d_in[1];
    const float* v    = (const float*)d_in[2];
    const float* Wq   = (const float*)d_in[3];
    const float* bq   = (const float*)d_in[4];
    const float* Wk   = (const float*)d_in[5];
    const float* bk   = (const float*)d_in[6];
    const float* Wv   = (const float*)d_in[7];
    const float* bv   = (const float*)d_in[8];
    const float* temp = (const float*)d_in[9];

    const int S = 1024, D = 768;
    const long long nE = 16LL * S * D;          // 12,582,912
    const long long nW = (long long)D * D;      // 589,824

    // ws layout (bytes), total 207,224,832 (round 1 proved >= 218 MB usable):
    //  [0, 50331648)          : {qhi,qlo} -> {khi,klo} -> scores fp32 (spills on)
    //  [50331648, 75497472)   : vhi (dead after VT; tail of scores region)
    //  [75497472, 176160768)  : Qhi,Qlo,Khi,Klo
    //  [176160768, 201326592) : VT bf16
    //  [201326592, ...)       : W splits
    char* ws = (char*)d_ws;
    ushort* qhi = (ushort*)ws;
    ushort* qlo = (ushort*)(ws + 25165824);
    float*  scores = (float*)ws;                  // 67,108,864 B
    ushort* vhi = (ushort*)(ws + 50331648);
    ushort* Qhi = (ushort*)(ws + 75497472);
    ushort* Qlo = Qhi + nE;
    ushort* Khi = Qlo + nE;
    ushort* Klo = Khi + nE;
    ushort* VT  = (ushort*)(ws + 176160768);
    ushort* W0  = (ushort*)(ws + 201326592);
    ushort* wqh = W0;
    ushort* wql = W0 + nW;
    ushort* wkh = W0 + 2 * nW;
    ushort* wkl = W0 + 3 * nW;
    ushort* wvh = W0 + 4 * nW;

    dim3 blk(256);

    // weight + v splits
    split_kernel<true ><<<288, blk, 0, stream>>>(Wq, wqh, wql, nW);
    split_kernel<true ><<<288, blk, 0, stream>>>(Wk, wkh, wkl, nW);
    split_kernel<false><<<288, blk, 0, stream>>>(Wv, wvh, nullptr, nW);
    split_kernel<false><<<2048, blk, 0, stream>>>(v, vhi, nullptr, nE);

    // VT[b][e][s] = sum_k Wv[e,k] v[b,s,k] + bv[e]   (M=768 rows=e, N=1024 cols=s)
    mfma_gemm<0, 2, 2><<<dim3(8, 6, 16), blk, 0, stream>>>(
        wvh, nullptr, vhi, nullptr, bv, VT, nullptr,
        768, 768, 768, 1024, 0, (long long)S * D, (long long)D * S);

    // Q projection (split): M=16384, N=768, K=768
    split_kernel<true><<<2048, blk, 0, stream>>>(q, qhi, qlo, nE);
    mfma_gemm<1, 1, 1><<<dim3(6, 128, 1), blk, 0, stream>>>(
        qhi, qlo, wqh, wql, bq, Qhi, Qlo,
        768, 768, 768, 768, 0, 0, 0);

    // K projection (split), reusing the q-split region
    split_kernel<true><<<2048, blk, 0, stream>>>(k, qhi, qlo, nE);
    mfma_gemm<1, 1, 1><<<dim3(6, 128, 1), blk, 0, stream>>>(
        qhi, qlo, wkh, wkl, bk, Khi, Klo,
        768, 768, 768, 768, 0, 0, 0);

    // scores[b] = Q[b] K[b]^T (split): M=N=1024, K=768, fp32 out
    mfma_gemm<1, 0, 0><<<dim3(8, 8, 16), blk, 0, stream>>>(
        Qhi, Qlo, Khi, Klo, nullptr, scores, nullptr,
        768, 768, 768, 1024,
        (long long)S * D, (long long)S * D, (long long)S * S);

    // masked softmax, bf16 P written in place (row stride stays 4096 B)
    softmax_diag<<<16 * S, blk, 0, stream>>>(scores, temp, S);

    // out[b] = P[b] VT[b]^T : M=1024(s), N=768(e), K=1024
    mfma_gemm<0, 0, 0><<<dim3(6, 8, 16), blk, 0, stream>>>(
        (const ushort*)scores, nullptr, VT, nullptr, nullptr, d_out, nullptr,
        1024, 2048, 1024, 768,
        2LL * S * S, (long long)D * S, (long long)S * D);
}

// Round 3
// 370.761 us; speedup vs baseline: 3.7689x; 1.1680x over previous
//
#include <hip/hip_runtime.h>
#include <hip/hip_bf16.h>
#include <math.h>

// LocalityAttention via split-bf16 MFMA.
// q,k,Wq,Wk,Q,K,scores use 2-term bf16 split (hi+lo, 3 MFMA passes) -> ~16-bit
// mantissa accuracy on the logits (noise ~8e-4, vs bf16-only ~0.15 which fails).
// v,Wv,V,P use plain bf16 (output-side error ~1e-2, under threshold).
// Round 3: XCD-chunked blockIdx swizzle on all GEMMs (PV was fetch-bound:
// 269 MB vs 56 MB minimum; per-batch working set fits one XCD's 4 MB L2).

typedef __attribute__((ext_vector_type(8))) short short8;
typedef __attribute__((ext_vector_type(4))) float f32x4;

__device__ __forceinline__ ushort f2bf(float x) {
    __hip_bfloat16 h = __float2bfloat16(x);
    return *(ushort*)&h;
}
__device__ __forceinline__ float bf2f(ushort u) {
    __hip_bfloat16 h;
    *(ushort*)&h = u;
    return __bfloat162float(h);
}

template<typename T>
__device__ __forceinline__ void async_copy16(T* lds, const T* g) {
    __builtin_amdgcn_global_load_lds(
        (const __attribute__((address_space(1))) unsigned int*)g,
        (__attribute__((address_space(3))) unsigned int*)lds, 16, 0, 0);
}

#define BM 128
#define BN 128
#define BK 32

// C[m,n] = sum_k A[m,k]*B[n,k]   (TRANSB everywhere: B staged row-major [n][k])
// SPLIT: A,B given as (hi,lo) bf16 pairs; accumulate hi*hi + hi*lo + lo*hi.
// EPI: 0 = fp32 store to C0; 1 = bf16 split store to C0(hi),C1(lo); 2 = bf16 to C0.
// BIAS: 0 none; 1 bias[col]; 2 bias[row].
template<int SPLIT, int EPI, int BIAS>
__global__ __launch_bounds__(256, 2)
void mfma_gemm(const ushort* __restrict__ Ah, const ushort* __restrict__ Al,
               const ushort* __restrict__ Bh, const ushort* __restrict__ Bl,
               const float* __restrict__ bias,
               void* __restrict__ C0, void* __restrict__ C1,
               int K, int lda, int ldb, int ldc,
               long long sA, long long sB, long long sC)
{
    __shared__ ushort sAh[BM * BK];
    __shared__ ushort sBh[BN * BK];
    __shared__ ushort sAl[SPLIT ? BM * BK : 4];
    __shared__ ushort sBl[SPLIT ? BN * BK : 4];

    const int tid = threadIdx.x;

    // XCD-chunked bijective swizzle: physical id p runs on XCD p%8; give that
    // XCD the contiguous logical chunk [(p%8)*cpx, ...). Requires nwg%8==0
    // (true for every launch below).
    const int gx = gridDim.x, gy = gridDim.y;
    const int nwg = gx * gy * gridDim.z;
    const int p = blockIdx.x + gx * (blockIdx.y + gy * blockIdx.z);
    const int cpx = nwg >> 3;
    const int l = (p & 7) * cpx + (p >> 3);
    const int bx = l % gx;
    const int by = (l / gx) % gy;
    const long long bz = l / (gx * gy);

    const int m0 = by * BM;
    const int n0 = bx * BN;

    const ushort* A0 = Ah + bz * sA;
    const ushort* B0 = Bh + bz * sB;
    const ushort* A1 = SPLIT ? Al + bz * sA : nullptr;
    const ushort* B1 = SPLIT ? Bl + bz * sB : nullptr;

    // loader: flat byte f = tid*16 + it*4096 -> row = f/64, slot = (f/16)&3
    // LDS is the swizzled layout: physical slot p holds global slot p^(row&3).
    const int lrow  = tid >> 2;
    const int lslot = tid & 3;

    const int lane = tid & 63;
    const int wv   = tid >> 6;
    const int wm   = wv >> 1, wn = wv & 1;
    const int fr   = lane & 15;       // fragment row (A) / col-row (B)
    const int fs   = lane >> 4;       // k-slot (8 bf16 = 16B each)
    const int sw   = fs ^ (fr & 3);   // swizzled read slot
    const int abase = (wm * 64 + fr) * BK + sw * 8;
    const int bbase = (wn * 64 + fr) * BK + sw * 8;

    f32x4 acc[4][4] = {};

    for (int kt = 0; kt < K; kt += BK) {
        #pragma unroll
        for (int it = 0; it < 2; ++it) {
            const int row = lrow + it * 64;
            const int gsl = (lslot ^ (row & 3)) << 3;       // element offset in row
            const size_t loff = (size_t)tid * 8 + (size_t)it * 2048;
            async_copy16(&sAh[loff], A0 + (size_t)(m0 + row) * lda + kt + gsl);
            async_copy16(&sBh[loff], B0 + (size_t)(n0 + row) * ldb + kt + gsl);
            if (SPLIT) {
                async_copy16(&sAl[loff], A1 + (size_t)(m0 + row) * lda + kt + gsl);
                async_copy16(&sBl[loff], B1 + (size_t)(n0 + row) * ldb + kt + gsl);
            }
        }
        __syncthreads();

        short8 ah[4], bh[4], al[4], bl[4];
        #pragma unroll
        for (int i = 0; i < 4; ++i) {
            ah[i] = *(const short8*)&sAh[abase + i * 512];
            bh[i] = *(const short8*)&sBh[bbase + i * 512];
            if (SPLIT) {
                al[i] = *(const short8*)&sAl[abase + i * 512];
                bl[i] = *(const short8*)&sBl[bbase + i * 512];
            }
        }
        #pragma unroll
        for (int mi = 0; mi < 4; ++mi)
            #pragma unroll
            for (int ni = 0; ni < 4; ++ni) {
                acc[mi][ni] = __builtin_amdgcn_mfma_f32_16x16x32_bf16(
                    ah[mi], bh[ni], acc[mi][ni], 0, 0, 0);
                if (SPLIT) {
                    acc[mi][ni] = __builtin_amdgcn_mfma_f32_16x16x32_bf16(
                        ah[mi], bl[ni], acc[mi][ni], 0, 0, 0);
                    acc[mi][ni] = __builtin_amdgcn_mfma_f32_16x16x32_bf16(
                        al[mi], bh[ni], acc[mi][ni], 0, 0, 0);
                }
            }
        __syncthreads();
    }

    // epilogue: D row = (lane>>4)*4 + r, col = lane&15 (verified m89 mapping)
    const int er = fs * 4;
    #pragma unroll
    for (int mi = 0; mi < 4; ++mi) {
        #pragma unroll
        for (int ni = 0; ni < 4; ++ni) {
            const int col = n0 + wn * 64 + ni * 16 + fr;
            #pragma unroll
            for (int r = 0; r < 4; ++r) {
                const int row = m0 + wm * 64 + mi * 16 + er + r;
                float vv = acc[mi][ni][r];
                if (BIAS == 1) vv += bias[col];
                if (BIAS == 2) vv += bias[row];
                const size_t idx = (size_t)bz * sC + (size_t)row * ldc + col;
                if (EPI == 0) {
                    ((float*)C0)[idx] = vv;
                } else if (EPI == 1) {
                    const ushort h = f2bf(vv);
                    ((ushort*)C0)[idx] = h;
                    ((ushort*)C1)[idx] = f2bf(vv - bf2f(h));
                } else {
                    ((ushort*)C0)[idx] = f2bf(vv);
                }
            }
        }
    }
}

// fp32 -> bf16 hi (+lo) split, vectorized
template<bool LO>
__global__ __launch_bounds__(256)
void split_kernel(const float* __restrict__ src, ushort* __restrict__ hi,
                  ushort* __restrict__ lo, long long n)
{
    long long i = ((long long)blockIdx.x * 256 + threadIdx.x) * 4;
    const long long stride = (long long)gridDim.x * 1024;
    for (; i < n; i += stride) {
        float4 v = *(const float4*)&src[i];
        float xs[4] = {v.x, v.y, v.z, v.w};
        ushort4 h, l;
        ushort hh[4], ll[4];
        #pragma unroll
        for (int j = 0; j < 4; ++j) {
            hh[j] = f2bf(xs[j]);
            if (LO) ll[j] = f2bf(xs[j] - bf2f(hh[j]));
        }
        h.x = hh[0]; h.y = hh[1]; h.z = hh[2]; h.w = hh[3];
        *(ushort4*)&hi[i] = h;
        if (LO) {
            l.x = ll[0]; l.y = ll[1]; l.z = ll[2]; l.w = ll[3];
            *(ushort4*)&lo[i] = l;
        }
    }
}

// Row softmax with diag mask; reads fp32 row, writes bf16 P IN-PLACE over the
// first half of the row (all reads complete before the first barrier).
__global__ __launch_bounds__(256)
void softmax_diag(float* __restrict__ P, const float* __restrict__ tptr, int S)
{
    const int row = blockIdx.x;
    const int i   = row % S;
    float* rp = P + (long long)row * S;
    const int tid = threadIdx.x;
    const float invt = 1.0f / tptr[0];

    float4 v = *(const float4*)&rp[tid * 4];
    float vals[4] = {v.x, v.y, v.z, v.w};
    #pragma unroll
    for (int j = 0; j < 4; ++j) {
        vals[j] *= invt;
        if (tid * 4 + j == i) vals[j] = -INFINITY;
    }

    float mx = fmaxf(fmaxf(vals[0], vals[1]), fmaxf(vals[2], vals[3]));
    #pragma unroll
    for (int off = 32; off > 0; off >>= 1)
        mx = fmaxf(mx, __shfl_down(mx, off, 64));

    __shared__ float smax[4], ssum[4];
    const int wv = tid >> 6, ln = tid & 63;
    if (ln == 0) smax[wv] = mx;
    __syncthreads();
    mx = fmaxf(fmaxf(smax[0], smax[1]), fmaxf(smax[2], smax[3]));

    float e[4];
    float s = 0.f;
    #pragma unroll
    for (int j = 0; j < 4; ++j) { e[j] = expf(vals[j] - mx); s += e[j]; }
    #pragma unroll
    for (int off = 32; off > 0; off >>= 1)
        s += __shfl_down(s, off, 64);
    if (ln == 0) ssum[wv] = s;
    __syncthreads();
    s = ssum[0] + ssum[1] + ssum[2] + ssum[3];

    const float inv = 1.0f / s;
    ushort4 o;
    o.x = f2bf(e[0] * inv);
    o.y = f2bf(e[1] * inv);
    o.z = f2bf(e[2] * inv);
    o.w = f2bf(e[3] * inv);
    *(ushort4*)&((ushort*)rp)[tid * 4] = o;
}

extern "C" void kernel_launch(void* const* d_in, const int* in_sizes, int n_in,
                              void* d_out, int out_size, void* d_ws, size_t ws_size,
                              hipStream_t stream)
{
    const float* q    = (const float*)d_in[0];
    const float* k    = (const float*)d_in[1];
    const float* v    = (const float*)d_in[2];
    const float* Wq   = (const float*)d_in[3];
    const float* bq   = (const float*)d_in[4];
    const float* Wk   = (const float*)d_in[5];
    const float* bk   = (const float*)d_in[6];
    const float* Wv   = (const float*)d_in[7];
    const float* bv   = (const float*)d_in[8];
    const float* temp = (const float*)d_in[9];

    const int S = 1024, D = 768;
    const long long nE = 16LL * S * D;          // 12,582,912
    const long long nW = (long long)D * D;      // 589,824

    // ws layout (bytes), total 207,224,832:
    //  [0, 50331648)          : {qhi,qlo} -> {khi,klo} -> scores fp32
    //  [50331648, 75497472)   : vhi (dead after VT; tail of scores region)
    //  [75497472, 176160768)  : Qhi,Qlo,Khi,Klo
    //  [176160768, 201326592) : VT bf16
    //  [201326592, ...)       : W splits
    char* ws = (char*)d_ws;
    ushort* qhi = (ushort*)ws;
    ushort* qlo = (ushort*)(ws + 25165824);
    float*  scores = (float*)ws;                  // 67,108,864 B
    ushort* vhi = (ushort*)(ws + 50331648);
    ushort* Qhi = (ushort*)(ws + 75497472);
    ushort* Qlo = Qhi + nE;
    ushort* Khi = Qlo + nE;
    ushort* Klo = Khi + nE;
    ushort* VT  = (ushort*)(ws + 176160768);
    ushort* W0  = (ushort*)(ws + 201326592);
    ushort* wqh = W0;
    ushort* wql = W0 + nW;
    ushort* wkh = W0 + 2 * nW;
    ushort* wkl = W0 + 3 * nW;
    ushort* wvh = W0 + 4 * nW;

    dim3 blk(256);

    // weight + v splits
    split_kernel<true ><<<288, blk, 0, stream>>>(Wq, wqh, wql, nW);
    split_kernel<true ><<<288, blk, 0, stream>>>(Wk, wkh, wkl, nW);
    split_kernel<false><<<288, blk, 0, stream>>>(Wv, wvh, nullptr, nW);
    split_kernel<false><<<2048, blk, 0, stream>>>(v, vhi, nullptr, nE);

    // VT[b][e][s] = sum_k Wv[e,k] v[b,s,k] + bv[e]   (M=768 rows=e, N=1024 cols=s)
    mfma_gemm<0, 2, 2><<<dim3(8, 6, 16), blk, 0, stream>>>(
        wvh, nullptr, vhi, nullptr, bv, VT, nullptr,
        768, 768, 768, 1024, 0, (long long)S * D, (long long)D * S);

    // Q projection (split): M=16384, N=768, K=768
    split_kernel<true><<<2048, blk, 0, stream>>>(q, qhi, qlo, nE);
    mfma_gemm<1, 1, 1><<<dim3(6, 128, 1), blk, 0, stream>>>(
        qhi, qlo, wqh, wql, bq, Qhi, Qlo,
        768, 768, 768, 768, 0, 0, 0);

    // K projection (split), reusing the q-split region
    split_kernel<true><<<2048, blk, 0, stream>>>(k, qhi, qlo, nE);
    mfma_gemm<1, 1, 1><<<dim3(6, 128, 1), blk, 0, stream>>>(
        qhi, qlo, wkh, wkl, bk, Khi, Klo,
        768, 768, 768, 768, 0, 0, 0);

    // scores[b] = Q[b] K[b]^T (split): M=N=1024, K=768, fp32 out
    mfma_gemm<1, 0, 0><<<dim3(8, 8, 16), blk, 0, stream>>>(
        Qhi, Qlo, Khi, Klo, nullptr, scores, nullptr,
        768, 768, 768, 1024,
        (long long)S * D, (long long)S * D, (long long)S * S);

    // masked softmax, bf16 P written in place (row stride stays 4096 B)
    softmax_diag<<<16 * S, blk, 0, stream>>>(scores, temp, S);

    // out[b] = P[b] VT[b]^T : M=1024(s), N=768(e), K=1024
    mfma_gemm<0, 0, 0><<<dim3(6, 8, 16), blk, 0, stream>>>(
        (const ushort*)scores, nullptr, VT, nullptr, nullptr, d_out, nullptr,
        1024, 2048, 1024, 768,
        2LL * S * S, (long long)D * S, (long long)S * D);
}

// Round 4
// 368.084 us; speedup vs baseline: 3.7963x; 1.0073x over previous
//
#include <hip/hip_runtime.h>
#include <hip/hip_bf16.h>
#include <math.h>

// LocalityAttention via split-bf16 MFMA, with the Q-projection algebraically
// folded away: softmax(Q K^T) = softmax(q G k^T + col-term) where G = Wq^T Wk
// (row-constant terms cancel in softmax). KG = k*G^T replaces the K
// projection at equal cost; the Q projection (58 GF split) is eliminated.
// q,k,G,KG,scores use 2-term bf16 split (3 MFMA passes, ~16-bit mantissa);
// v,Wv,V,P plain bf16.

typedef __attribute__((ext_vector_type(8))) short short8;
typedef __attribute__((ext_vector_type(4))) float f32x4;

__device__ __forceinline__ ushort f2bf(float x) {
    __hip_bfloat16 h = __float2bfloat16(x);
    return *(ushort*)&h;
}
__device__ __forceinline__ float bf2f(ushort u) {
    __hip_bfloat16 h;
    *(ushort*)&h = u;
    return __bfloat162float(h);
}

template<typename T>
__device__ __forceinline__ void async_copy16(T* lds, const T* g) {
    __builtin_amdgcn_global_load_lds(
        (const __attribute__((address_space(1))) unsigned int*)g,
        (__attribute__((address_space(3))) unsigned int*)lds, 16, 0, 0);
}

#define BM 128
#define BN 128
#define BK 32

// C[m,n] = sum_k A[m,k]*B[n,k]  (TRANSB staging: B row-major [n][k])
// SPLIT: A,B as (hi,lo) bf16 pairs; accumulate hi*hi + hi*lo + lo*hi.
// EPI: 0 fp32->C0; 1 bf16 split->C0,C1; 2 bf16->C0.  BIAS: 0 none;1 col;2 row.
template<int SPLIT, int EPI, int BIAS>
__global__ __launch_bounds__(256, 3)
void mfma_gemm(const ushort* __restrict__ Ah, const ushort* __restrict__ Al,
               const ushort* __restrict__ Bh, const ushort* __restrict__ Bl,
               const float* __restrict__ bias,
               void* __restrict__ C0, void* __restrict__ C1,
               int K, int lda, int ldb, int ldc,
               long long sA, long long sB, long long sC)
{
    __shared__ ushort sAh[BM * BK];
    __shared__ ushort sBh[BN * BK];
    __shared__ ushort sAl[SPLIT ? BM * BK : 4];
    __shared__ ushort sBl[SPLIT ? BN * BK : 4];

    const int tid = threadIdx.x;

    // XCD-chunked bijective swizzle (only when nwg%8==0; G GEMM has nwg=36).
    const int gx = gridDim.x, gy = gridDim.y;
    const int nwg = gx * gy * gridDim.z;
    const int p = blockIdx.x + gx * (blockIdx.y + gy * blockIdx.z);
    const int cpx = nwg >> 3;
    const int l = (nwg & 7) ? p : (p & 7) * cpx + (p >> 3);
    const int bx = l % gx;
    const int by = (l / gx) % gy;
    const long long bz = l / (gx * gy);

    const int m0 = by * BM;
    const int n0 = bx * BN;

    const ushort* A0 = Ah + bz * sA;
    const ushort* B0 = Bh + bz * sB;
    const ushort* A1 = SPLIT ? Al + bz * sA : nullptr;
    const ushort* B1 = SPLIT ? Bl + bz * sB : nullptr;

    const int lrow  = tid >> 2;
    const int lslot = tid & 3;

    const int lane = tid & 63;
    const int wv   = tid >> 6;
    const int wm   = wv >> 1, wn = wv & 1;
    const int fr   = lane & 15;
    const int fs   = lane >> 4;
    const int sw   = fs ^ (fr & 3);
    const int abase = (wm * 64 + fr) * BK + sw * 8;
    const int bbase = (wn * 64 + fr) * BK + sw * 8;

    f32x4 acc[4][4] = {};

    for (int kt = 0; kt < K; kt += BK) {
        #pragma unroll
        for (int it = 0; it < 2; ++it) {
            const int row = lrow + it * 64;
            const int gsl = (lslot ^ (row & 3)) << 3;
            const size_t loff = (size_t)tid * 8 + (size_t)it * 2048;
            async_copy16(&sAh[loff], A0 + (size_t)(m0 + row) * lda + kt + gsl);
            async_copy16(&sBh[loff], B0 + (size_t)(n0 + row) * ldb + kt + gsl);
            if (SPLIT) {
                async_copy16(&sAl[loff], A1 + (size_t)(m0 + row) * lda + kt + gsl);
                async_copy16(&sBl[loff], B1 + (size_t)(n0 + row) * ldb + kt + gsl);
            }
        }
        __syncthreads();

        short8 ah[4], bh[4], al[4], bl[4];
        #pragma unroll
        for (int i = 0; i < 4; ++i) {
            ah[i] = *(const short8*)&sAh[abase + i * 512];
            bh[i] = *(const short8*)&sBh[bbase + i * 512];
            if (SPLIT) {
                al[i] = *(const short8*)&sAl[abase + i * 512];
                bl[i] = *(const short8*)&sBl[bbase + i * 512];
            }
        }
        #pragma unroll
        for (int mi = 0; mi < 4; ++mi)
            #pragma unroll
            for (int ni = 0; ni < 4; ++ni) {
                acc[mi][ni] = __builtin_amdgcn_mfma_f32_16x16x32_bf16(
                    ah[mi], bh[ni], acc[mi][ni], 0, 0, 0);
                if (SPLIT) {
                    acc[mi][ni] = __builtin_amdgcn_mfma_f32_16x16x32_bf16(
                        ah[mi], bl[ni], acc[mi][ni], 0, 0, 0);
                    acc[mi][ni] = __builtin_amdgcn_mfma_f32_16x16x32_bf16(
                        al[mi], bh[ni], acc[mi][ni], 0, 0, 0);
                }
            }
        __syncthreads();
    }

    const int er = fs * 4;
    #pragma unroll
    for (int mi = 0; mi < 4; ++mi) {
        #pragma unroll
        for (int ni = 0; ni < 4; ++ni) {
            const int col = n0 + wn * 64 + ni * 16 + fr;
            #pragma unroll
            for (int r = 0; r < 4; ++r) {
                const int row = m0 + wm * 64 + mi * 16 + er + r;
                float vv = acc[mi][ni][r];
                if (BIAS == 1) vv += bias[col];
                if (BIAS == 2) vv += bias[row];
                const size_t idx = (size_t)bz * sC + (size_t)row * ldc + col;
                if (EPI == 0) {
                    ((float*)C0)[idx] = vv;
                } else if (EPI == 1) {
                    const ushort h = f2bf(vv);
                    ((ushort*)C0)[idx] = h;
                    ((ushort*)C1)[idx] = f2bf(vv - bf2f(h));
                } else {
                    ((ushort*)C0)[idx] = f2bf(vv);
                }
            }
        }
    }
}

// fp32 -> bf16 hi (+lo) split, vectorized
template<bool LO>
__global__ __launch_bounds__(256)
void split_kernel(const float* __restrict__ src, ushort* __restrict__ hi,
                  ushort* __restrict__ lo, long long n)
{
    long long i = ((long long)blockIdx.x * 256 + threadIdx.x) * 4;
    const long long stride = (long long)gridDim.x * 1024;
    for (; i < n; i += stride) {
        float4 v = *(const float4*)&src[i];
        float xs[4] = {v.x, v.y, v.z, v.w};
        ushort4 h, l;
        ushort hh[4], ll[4];
        #pragma unroll
        for (int j = 0; j < 4; ++j) {
            hh[j] = f2bf(xs[j]);
            if (LO) ll[j] = f2bf(xs[j] - bf2f(hh[j]));
        }
        h.x = hh[0]; h.y = hh[1]; h.z = hh[2]; h.w = hh[3];
        *(ushort4*)&hi[i] = h;
        if (LO) {
            l.x = ll[0]; l.y = ll[1]; l.z = ll[2]; l.w = ll[3];
            *(ushort4*)&lo[i] = l;
        }
    }
}

// 64x64-tile transpose + bf16 split: dst_hi/lo[c][r] = split(src[r][c]); n=768
__global__ __launch_bounds__(256)
void transpose_split(const float* __restrict__ src, ushort* __restrict__ hi,
                     ushort* __restrict__ lo, int n)
{
    __shared__ float t[64][65];
    const int tx = threadIdx.x & 63, ty = threadIdx.x >> 6;
    const int r0 = blockIdx.y * 64, c0 = blockIdx.x * 64;
    #pragma unroll
    for (int r = 0; r < 16; ++r) {
        const int row = ty * 16 + r;
        t[row][tx] = src[(size_t)(r0 + row) * n + c0 + tx];
    }
    __syncthreads();
    #pragma unroll
    for (int r = 0; r < 16; ++r) {
        const int orow = ty * 16 + r;            // original col
        const float val = t[tx][orow];
        const ushort h = f2bf(val);
        hi[(size_t)(c0 + orow) * n + r0 + tx] = h;
        lo[(size_t)(c0 + orow) * n + r0 + tx] = f2bf(val - bf2f(h));
    }
}

// colvec[d] = sum_e WkT[d][e]*bq[e]   (one wave per row; grid 192 x 4 waves)
__global__ __launch_bounds__(256)
void colvec_kernel(const ushort* __restrict__ WkTh, const ushort* __restrict__ WkTl,
                   const float* __restrict__ bq, float* __restrict__ colvec, int n)
{
    const int wv = threadIdx.x >> 6, lane = threadIdx.x & 63;
    const int d = blockIdx.x * 4 + wv;
    float s = 0.f;
    for (int e = lane; e < n; e += 64)
        s += (bf2f(WkTh[(size_t)d * n + e]) + bf2f(WkTl[(size_t)d * n + e])) * bq[e];
    #pragma unroll
    for (int off = 32; off; off >>= 1) s += __shfl_down(s, off, 64);
    if (lane == 0) colvec[d] = s;
}

// cterm[row] = dot(k[row,:], colvec)  for 16384 rows of 768 (grid 4096 x 4 waves)
__global__ __launch_bounds__(256)
void cterm_kernel(const float* __restrict__ k, const float* __restrict__ colvec,
                  float* __restrict__ cterm)
{
    const int wv = threadIdx.x >> 6, lane = threadIdx.x & 63;
    const long long row = (long long)blockIdx.x * 4 + wv;
    const float* kp = k + row * 768;
    float s = 0.f;
    #pragma unroll
    for (int i = 0; i < 3; ++i) {
        const float4 a = *(const float4*)&kp[lane * 4 + i * 256];
        const float4 c = *(const float4*)&colvec[lane * 4 + i * 256];
        s += a.x * c.x + a.y * c.y + a.z * c.z + a.w * c.w;
    }
    #pragma unroll
    for (int off = 32; off; off >>= 1) s += __shfl_down(s, off, 64);
    if (lane == 0) cterm[row] = s;
}

// Row softmax with diag mask + per-column bias term; reads fp32 row, writes
// bf16 P in place over the first half of the row.
__global__ __launch_bounds__(256)
void softmax_diag(float* __restrict__ P, const float* __restrict__ tptr,
                  const float* __restrict__ cterm, int S)
{
    const int row = blockIdx.x;           // b*S + i
    const int i   = row % S;
    float* rp = P + (long long)row * S;
    const int tid = threadIdx.x;
    const float invt = 1.0f / tptr[0];

    const float4 v  = *(const float4*)&rp[tid * 4];
    const float4 ct = *(const float4*)&cterm[(long long)(row / S) * S + tid * 4];
    float vals[4] = {v.x + ct.x, v.y + ct.y, v.z + ct.z, v.w + ct.w};
    #pragma unroll
    for (int j = 0; j < 4; ++j) {
        vals[j] *= invt;
        if (tid * 4 + j == i) vals[j] = -INFINITY;
    }

    float mx = fmaxf(fmaxf(vals[0], vals[1]), fmaxf(vals[2], vals[3]));
    #pragma unroll
    for (int off = 32; off > 0; off >>= 1)
        mx = fmaxf(mx, __shfl_down(mx, off, 64));

    __shared__ float smax[4], ssum[4];
    const int wv = tid >> 6, ln = tid & 63;
    if (ln == 0) smax[wv] = mx;
    __syncthreads();
    mx = fmaxf(fmaxf(smax[0], smax[1]), fmaxf(smax[2], smax[3]));

    float e[4];
    float s = 0.f;
    #pragma unroll
    for (int j = 0; j < 4; ++j) { e[j] = expf(vals[j] - mx); s += e[j]; }
    #pragma unroll
    for (int off = 32; off > 0; off >>= 1)
        s += __shfl_down(s, off, 64);
    if (ln == 0) ssum[wv] = s;
    __syncthreads();
    s = ssum[0] + ssum[1] + ssum[2] + ssum[3];

    const float inv = 1.0f / s;
    ushort4 o;
    o.x = f2bf(e[0] * inv);
    o.y = f2bf(e[1] * inv);
    o.z = f2bf(e[2] * inv);
    o.w = f2bf(e[3] * inv);
    *(ushort4*)&((ushort*)rp)[tid * 4] = o;
}

extern "C" void kernel_launch(void* const* d_in, const int* in_sizes, int n_in,
                              void* d_out, int out_size, void* d_ws, size_t ws_size,
                              hipStream_t stream)
{
    const float* q    = (const float*)d_in[0];
    const float* k    = (const float*)d_in[1];
    const float* v    = (const float*)d_in[2];
    const float* Wq   = (const float*)d_in[3];
    const float* bq   = (const float*)d_in[4];
    const float* Wk   = (const float*)d_in[5];
    const float* bk   = (const float*)d_in[6];   // row-constant -> cancels in softmax
    const float* Wv   = (const float*)d_in[7];
    const float* bv   = (const float*)d_in[8];
    const float* temp = (const float*)d_in[9];
    (void)bk;

    const int S = 1024, D = 768;
    const long long nE = 16LL * S * D;

    // ws layout (bytes), max end 202,574,848 (< proven 207,224,832):
    //  qhi 0  qlo 24M | khi 48M klo 72M | vhi 96M (dead after VT; then
    //  WqT/WkT/G splits live there) | KGhi 120M KGlo 144M | VT 168M |
    //  wvh/colvec/cterm at 192M | scores fp32 64MiB at 48M (over dead
    //  khi/klo/weights after KG GEMM).
    char* ws = (char*)d_ws;
    ushort* qhi  = (ushort*)(ws + 0);
    ushort* qlo  = (ushort*)(ws + 25165824);
    ushort* khi  = (ushort*)(ws + 50331648);
    ushort* klo  = (ushort*)(ws + 75497472);
    ushort* vhi  = (ushort*)(ws + 100663296);
    ushort* WqTh = (ushort*)(ws + 100663296);   // after VT GEMM, vhi is dead
    ushort* WqTl = (ushort*)(ws + 101842944);
    ushort* WkTh = (ushort*)(ws + 103022592);
    ushort* WkTl = (ushort*)(ws + 104202240);
    ushort* Ghi  = (ushort*)(ws + 105381888);
    ushort* Glo  = (ushort*)(ws + 106561536);
    ushort* KGhi = (ushort*)(ws + 125829120);
    ushort* KGlo = (ushort*)(ws + 150994944);
    ushort* VT   = (ushort*)(ws + 176160768);
    ushort* wvh  = (ushort*)(ws + 201326592);
    float* colvec = (float*)(ws + 202506240);
    float* cterm  = (float*)(ws + 202509312);
    float* scores = (float*)(ws + 50331648);

    dim3 blk(256);

    // stage inputs
    split_kernel<false><<<288,  blk, 0, stream>>>(Wv, wvh, nullptr, (long long)D * D);
    split_kernel<false><<<2048, blk, 0, stream>>>(v, vhi, nullptr, nE);
    split_kernel<true ><<<2048, blk, 0, stream>>>(q, qhi, qlo, nE);
    split_kernel<true ><<<2048, blk, 0, stream>>>(k, khi, klo, nE);

    // VT[b][e][s] = sum_d Wv[e,d] v[b,s,d] + bv[e]  (frees vhi region)
    mfma_gemm<0, 2, 2><<<dim3(8, 6, 16), blk, 0, stream>>>(
        wvh, nullptr, vhi, nullptr, bv, VT, nullptr,
        768, 768, 768, 1024, 0, (long long)S * D, (long long)D * S);

    // weight transposes into the dead vhi region
    transpose_split<<<dim3(12, 12), blk, 0, stream>>>(Wq, WqTh, WqTl, D);
    transpose_split<<<dim3(12, 12), blk, 0, stream>>>(Wk, WkTh, WkTl, D);

    // bias column-term: colvec = WkT*bq ; cterm[b,j] = k[b,j]·colvec
    colvec_kernel<<<192,  blk, 0, stream>>>(WkTh, WkTl, bq, colvec, D);
    cterm_kernel <<<4096, blk, 0, stream>>>(k, colvec, cterm);

    // G[d,d'] = sum_e Wq[e,d] Wk[e,d']  (split 3-pass, split output)
    mfma_gemm<1, 1, 0><<<dim3(6, 6, 1), blk, 0, stream>>>(
        WqTh, WqTl, WkTh, WkTl, nullptr, Ghi, Glo,
        768, 768, 768, 768, 0, 0, 0);

    // KG[j,d] = sum_d' k[j,d'] G[d,d']  (M=16384 flat; frees khi/klo + G)
    mfma_gemm<1, 1, 0><<<dim3(6, 128, 1), blk, 0, stream>>>(
        khi, klo, Ghi, Glo, nullptr, KGhi, KGlo,
        768, 768, 768, 768, 0, 0, 0);

    // scores[b] = q[b] (KG[b])^T  (== Q K^T minus softmax-invariant terms)
    mfma_gemm<1, 0, 0><<<dim3(8, 8, 16), blk, 0, stream>>>(
        qhi, qlo, KGhi, KGlo, nullptr, scores, nullptr,
        768, 768, 768, 1024,
        (long long)S * D, (long long)S * D, (long long)S * S);

    // masked softmax (+ column bias term), bf16 P written in place
    softmax_diag<<<16 * S, blk, 0, stream>>>(scores, temp, cterm, S);

    // out[b] = P[b] VT[b]^T
    mfma_gemm<0, 0, 0><<<dim3(6, 8, 16), blk, 0, stream>>>(
        (const ushort*)scores, nullptr, VT, nullptr, nullptr, d_out, nullptr,
        1024, 2048, 1024, 768,
        2LL * S * S, (long long)D * S, (long long)S * D);
}

// Round 5
// 246.225 us; speedup vs baseline: 5.6751x; 1.4949x over previous
//
#include <hip/hip_runtime.h>
#include <hip/hip_bf16.h>
#include <math.h>

// LocalityAttention, fp16 single-pass MFMA everywhere.
// Q-projection folded away: softmax(Q K^T) = softmax(q G k^T + colterm),
// G = Wq^T Wk; KG = k G^T replaces the K projection.
// fp16 (11-bit mantissa) logit noise std ~0.02-0.03 << 0.105 threshold;
// PV path (P,VT fp16) is 8x more accurate than the old bf16 path.

typedef _Float16 f16x8 __attribute__((ext_vector_type(8)));
typedef _Float16 f16x4 __attribute__((ext_vector_type(4)));
typedef __attribute__((ext_vector_type(4))) float f32x4;

template<typename T>
__device__ __forceinline__ void async_copy16(T* lds, const T* g) {
    __builtin_amdgcn_global_load_lds(
        (const __attribute__((address_space(1))) unsigned int*)g,
        (__attribute__((address_space(3))) unsigned int*)lds, 16, 0, 0);
}

#define BM 128
#define BN 128
#define BK 32

// C[m,n] = sum_k A[m,k]*B[n,k]  (B staged row-major [n][k])
// EPI: 0 fp32->C0; 1 fp16->C0.  BIAS: 0 none; 1 bias[col]; 2 bias[row].
template<int EPI, int BIAS>
__global__ __launch_bounds__(256, 2)
void mfma_gemm(const _Float16* __restrict__ A, const _Float16* __restrict__ B,
               const float* __restrict__ bias,
               void* __restrict__ C0,
               int K, int lda, int ldb, int ldc,
               long long sA, long long sB, long long sC)
{
    __shared__ _Float16 sAh[BM * BK];
    __shared__ _Float16 sBh[BN * BK];

    const int tid = threadIdx.x;

    // XCD-chunked bijective swizzle (skip when nwg%8 != 0, e.g. G GEMM's 36).
    const int gx = gridDim.x, gy = gridDim.y;
    const int nwg = gx * gy * gridDim.z;
    const int p = blockIdx.x + gx * (blockIdx.y + gy * blockIdx.z);
    const int cpx = nwg >> 3;
    const int l = (nwg & 7) ? p : (p & 7) * cpx + (p >> 3);
    const int bx = l % gx;
    const int by = (l / gx) % gy;
    const long long bz = l / (gx * gy);

    const int m0 = by * BM;
    const int n0 = bx * BN;

    const _Float16* A0 = A + bz * sA;
    const _Float16* B0 = B + bz * sB;

    // loader: flat 16B chunk per thread per it; LDS slot XOR-swizzled by row.
    const int lrow  = tid >> 2;
    const int lslot = tid & 3;

    const int lane = tid & 63;
    const int wv   = tid >> 6;
    const int wm   = wv >> 1, wn = wv & 1;
    const int fr   = lane & 15;
    const int fs   = lane >> 4;
    const int sw   = fs ^ (fr & 3);
    const int abase = (wm * 64 + fr) * BK + sw * 8;
    const int bbase = (wn * 64 + fr) * BK + sw * 8;

    f32x4 acc[4][4] = {};

    for (int kt = 0; kt < K; kt += BK) {
        #pragma unroll
        for (int it = 0; it < 2; ++it) {
            const int row = lrow + it * 64;
            const int gsl = (lslot ^ (row & 3)) << 3;
            const size_t loff = (size_t)tid * 8 + (size_t)it * 2048;
            async_copy16(&sAh[loff], A0 + (size_t)(m0 + row) * lda + kt + gsl);
            async_copy16(&sBh[loff], B0 + (size_t)(n0 + row) * ldb + kt + gsl);
        }
        __syncthreads();

        f16x8 ah[4], bh[4];
        #pragma unroll
        for (int i = 0; i < 4; ++i) {
            ah[i] = *(const f16x8*)&sAh[abase + i * 512];
            bh[i] = *(const f16x8*)&sBh[bbase + i * 512];
        }
        #pragma unroll
        for (int mi = 0; mi < 4; ++mi)
            #pragma unroll
            for (int ni = 0; ni < 4; ++ni)
                acc[mi][ni] = __builtin_amdgcn_mfma_f32_16x16x32_f16(
                    ah[mi], bh[ni], acc[mi][ni], 0, 0, 0);
        __syncthreads();
    }

    // D mapping: row=(lane>>4)*4+r, col=lane&15 (verified m89)
    const int er = fs * 4;
    #pragma unroll
    for (int mi = 0; mi < 4; ++mi) {
        #pragma unroll
        for (int ni = 0; ni < 4; ++ni) {
            const int col = n0 + wn * 64 + ni * 16 + fr;
            #pragma unroll
            for (int r = 0; r < 4; ++r) {
                const int row = m0 + wm * 64 + mi * 16 + er + r;
                float vv = acc[mi][ni][r];
                if (BIAS == 1) vv += bias[col];
                if (BIAS == 2) vv += bias[row];
                const size_t idx = (size_t)bz * sC + (size_t)row * ldc + col;
                if (EPI == 0) ((float*)C0)[idx] = vv;
                else          ((_Float16*)C0)[idx] = (_Float16)vv;
            }
        }
    }
}

// fp32 -> fp16 convert, 8 elements/thread
__global__ __launch_bounds__(256)
void tof16_kernel(const float* __restrict__ src, _Float16* __restrict__ dst,
                  long long n)
{
    long long i = ((long long)blockIdx.x * 256 + threadIdx.x) * 8;
    const long long stride = (long long)gridDim.x * 2048;
    for (; i < n; i += stride) {
        const float4 a = *(const float4*)&src[i];
        const float4 b = *(const float4*)&src[i + 4];
        f16x8 o;
        o[0] = (_Float16)a.x; o[1] = (_Float16)a.y;
        o[2] = (_Float16)a.z; o[3] = (_Float16)a.w;
        o[4] = (_Float16)b.x; o[5] = (_Float16)b.y;
        o[6] = (_Float16)b.z; o[7] = (_Float16)b.w;
        *(f16x8*)&dst[i] = o;
    }
}

// 64x64-tile transpose to fp16: dst[c][r] = src[r][c]; n=768
__global__ __launch_bounds__(256)
void transpose_f16(const float* __restrict__ src, _Float16* __restrict__ dst, int n)
{
    __shared__ float t[64][65];
    const int tx = threadIdx.x & 63, ty = threadIdx.x >> 6;
    const int r0 = blockIdx.y * 64, c0 = blockIdx.x * 64;
    #pragma unroll
    for (int r = 0; r < 16; ++r) {
        const int row = ty * 16 + r;
        t[row][tx] = src[(size_t)(r0 + row) * n + c0 + tx];
    }
    __syncthreads();
    #pragma unroll
    for (int r = 0; r < 16; ++r) {
        const int orow = ty * 16 + r;
        dst[(size_t)(c0 + orow) * n + r0 + tx] = (_Float16)t[tx][orow];
    }
}

// colvec[d] = sum_e WkT[d][e]*bq[e]
__global__ __launch_bounds__(256)
void colvec_kernel(const _Float16* __restrict__ WkT, const float* __restrict__ bq,
                   float* __restrict__ colvec, int n)
{
    const int wv = threadIdx.x >> 6, lane = threadIdx.x & 63;
    const int d = blockIdx.x * 4 + wv;
    float s = 0.f;
    for (int e = lane; e < n; e += 64)
        s += (float)WkT[(size_t)d * n + e] * bq[e];
    #pragma unroll
    for (int off = 32; off; off >>= 1) s += __shfl_down(s, off, 64);
    if (lane == 0) colvec[d] = s;
}

// cterm[row] = dot(k[row,:], colvec)  (fp32 inputs)
__global__ __launch_bounds__(256)
void cterm_kernel(const float* __restrict__ k, const float* __restrict__ colvec,
                  float* __restrict__ cterm)
{
    const int wv = threadIdx.x >> 6, lane = threadIdx.x & 63;
    const long long row = (long long)blockIdx.x * 4 + wv;
    const float* kp = k + row * 768;
    float s = 0.f;
    #pragma unroll
    for (int i = 0; i < 3; ++i) {
        const float4 a = *(const float4*)&kp[lane * 4 + i * 256];
        const float4 c = *(const float4*)&colvec[lane * 4 + i * 256];
        s += a.x * c.x + a.y * c.y + a.z * c.z + a.w * c.w;
    }
    #pragma unroll
    for (int off = 32; off; off >>= 1) s += __shfl_down(s, off, 64);
    if (lane == 0) cterm[row] = s;
}

// Row softmax with diag mask + per-column bias term; reads fp32 row, writes
// fp16 P in place over the first quarter of the row (reads precede writes).
__global__ __launch_bounds__(256)
void softmax_diag(float* __restrict__ P, const float* __restrict__ tptr,
                  const float* __restrict__ cterm, int S)
{
    const int row = blockIdx.x;           // b*S + i
    const int i   = row % S;
    float* rp = P + (long long)row * S;
    const int tid = threadIdx.x;
    const float invt = 1.0f / tptr[0];

    const float4 v  = *(const float4*)&rp[tid * 4];
    const float4 ct = *(const float4*)&cterm[(long long)(row / S) * S + tid * 4];
    float vals[4] = {v.x + ct.x, v.y + ct.y, v.z + ct.z, v.w + ct.w};
    #pragma unroll
    for (int j = 0; j < 4; ++j) {
        vals[j] *= invt;
        if (tid * 4 + j == i) vals[j] = -INFINITY;
    }

    float mx = fmaxf(fmaxf(vals[0], vals[1]), fmaxf(vals[2], vals[3]));
    #pragma unroll
    for (int off = 32; off > 0; off >>= 1)
        mx = fmaxf(mx, __shfl_down(mx, off, 64));

    __shared__ float smax[4], ssum[4];
    const int wv = tid >> 6, ln = tid & 63;
    if (ln == 0) smax[wv] = mx;
    __syncthreads();
    mx = fmaxf(fmaxf(smax[0], smax[1]), fmaxf(smax[2], smax[3]));

    float e[4];
    float s = 0.f;
    #pragma unroll
    for (int j = 0; j < 4; ++j) { e[j] = expf(vals[j] - mx); s += e[j]; }
    #pragma unroll
    for (int off = 32; off > 0; off >>= 1)
        s += __shfl_down(s, off, 64);
    if (ln == 0) ssum[wv] = s;
    __syncthreads();
    s = ssum[0] + ssum[1] + ssum[2] + ssum[3];

    const float inv = 1.0f / s;
    f16x4 o;
    o[0] = (_Float16)(e[0] * inv);
    o[1] = (_Float16)(e[1] * inv);
    o[2] = (_Float16)(e[2] * inv);
    o[3] = (_Float16)(e[3] * inv);
    *(f16x4*)&((_Float16*)rp)[tid * 4] = o;
}

extern "C" void kernel_launch(void* const* d_in, const int* in_sizes, int n_in,
                              void* d_out, int out_size, void* d_ws, size_t ws_size,
                              hipStream_t stream)
{
    const float* q    = (const float*)d_in[0];
    const float* k    = (const float*)d_in[1];
    const float* v    = (const float*)d_in[2];
    const float* Wq   = (const float*)d_in[3];
    const float* bq   = (const float*)d_in[4];
    const float* Wk   = (const float*)d_in[5];
    const float* bk   = (const float*)d_in[6];   // row-constant -> cancels in softmax
    const float* Wv   = (const float*)d_in[7];
    const float* bv   = (const float*)d_in[8];
    const float* temp = (const float*)d_in[9];
    (void)bk;

    const int S = 1024, D = 768;
    const long long nE = 16LL * S * D;           // 12,582,912
    const long long nW = (long long)D * D;       // 589,824

    // ws layout (bytes), end 197,725,184 (< proven 202,574,848). No aliasing.
    char* ws = (char*)d_ws;
    _Float16* qh  = (_Float16*)(ws + 0);          // 24 MB
    _Float16* kh  = (_Float16*)(ws + 25165824);   // 24 MB
    _Float16* vh  = (_Float16*)(ws + 50331648);   // 24 MB
    _Float16* VT  = (_Float16*)(ws + 75497472);   // 24 MB
    _Float16* KG  = (_Float16*)(ws + 100663296);  // 24 MB
    float*  scores = (float*)(ws + 125829120);    // 64 MiB
    _Float16* wvh = (_Float16*)(ws + 192937984);  // 1.125 MB
    _Float16* WqT = (_Float16*)(ws + 194117632);
    _Float16* WkT = (_Float16*)(ws + 195297280);
    _Float16* G   = (_Float16*)(ws + 196476928);
    float* colvec = (float*)(ws + 197656576);
    float* cterm  = (float*)(ws + 197659648);

    dim3 blk(256);

    // input conversions / transposes
    tof16_kernel<<<1024, blk, 0, stream>>>(q, qh, nE);
    tof16_kernel<<<1024, blk, 0, stream>>>(k, kh, nE);
    tof16_kernel<<<1024, blk, 0, stream>>>(v, vh, nE);
    tof16_kernel<<<288,  blk, 0, stream>>>(Wv, wvh, nW);
    transpose_f16<<<dim3(12, 12), blk, 0, stream>>>(Wq, WqT, D);
    transpose_f16<<<dim3(12, 12), blk, 0, stream>>>(Wk, WkT, D);

    // bias column-term: colvec = WkT*bq ; cterm[b,j] = k[b,j]·colvec
    colvec_kernel<<<192,  blk, 0, stream>>>(WkT, bq, colvec, D);
    cterm_kernel <<<4096, blk, 0, stream>>>(k, colvec, cterm);

    // VT[b][e][s] = sum_d Wv[e,d] v[b,s,d] + bv[e]
    mfma_gemm<1, 2><<<dim3(8, 6, 16), blk, 0, stream>>>(
        wvh, vh, bv, VT,
        768, 768, 768, 1024, 0, (long long)S * D, (long long)D * S);

    // G[d,d'] = sum_e Wq[e,d] Wk[e,d']
    mfma_gemm<1, 0><<<dim3(6, 6, 1), blk, 0, stream>>>(
        WqT, WkT, nullptr, G,
        768, 768, 768, 768, 0, 0, 0);

    // KG[j,d] = sum_d' k[j,d'] G[d,d']  (M = 16384 flat)
    mfma_gemm<1, 0><<<dim3(6, 128, 1), blk, 0, stream>>>(
        kh, G, nullptr, KG,
        768, 768, 768, 768, 0, 0, 0);

    // scores[b] = q[b] (KG[b])^T
    mfma_gemm<0, 0><<<dim3(8, 8, 16), blk, 0, stream>>>(
        qh, KG, nullptr, scores,
        768, 768, 768, 1024,
        (long long)S * D, (long long)S * D, (long long)S * S);

    // masked softmax (+ column bias term), fp16 P written in place
    softmax_diag<<<16 * S, blk, 0, stream>>>(scores, temp, cterm, S);

    // out[b] = P[b] VT[b]^T   (P rows: 1024 fp16 in a 4096B-stride row)
    mfma_gemm<0, 0><<<dim3(6, 8, 16), blk, 0, stream>>>(
        (const _Float16*)scores, VT, nullptr, d_out,
        1024, 2048, 1024, 768,
        2LL * S * S, (long long)D * S, (long long)S * D);
}